// Round 11
// baseline (14569.965 us; speedup 1.0000x reference)
//
#include <hip/hip_runtime.h>
#include <hip/hip_fp16.h>

#define B_   64
#define T_   512
#define DINc 512
#define D_   512
#define NWG  16
#define JS   32   // output columns per workgroup in scan

typedef _Float16 half8 __attribute__((ext_vector_type(8)));
typedef _Float16 half4 __attribute__((ext_vector_type(4)));
typedef float   floatx4 __attribute__((ext_vector_type(4)));
typedef unsigned uintx4 __attribute__((ext_vector_type(4)));

#define WAITV(N) asm volatile("s_waitcnt vmcnt(" #N ")" ::: "memory")
#define SCB()    __builtin_amdgcn_sched_barrier(0)

// ---------------- X convert + transpose: Xh[m][k] = (f16) X[b][t][k], m = t*64+b ----------------
__global__ __launch_bounds__(256) void k_cvtX(const float* __restrict__ X, _Float16* __restrict__ Xh) {
    int idx = blockIdx.x * 256 + threadIdx.x;
    int m  = idx >> 6;
    int k8 = idx & 63;
    int b = m & 63, t = m >> 6;
    const float* src = X + ((size_t)(b * T_ + t)) * DINc + k8 * 8;
    float4 f0 = *(const float4*)(src);
    float4 f1 = *(const float4*)(src + 4);
    half8 h;
    h[0] = (_Float16)f0.x; h[1] = (_Float16)f0.y; h[2] = (_Float16)f0.z; h[3] = (_Float16)f0.w;
    h[4] = (_Float16)f1.x; h[5] = (_Float16)f1.y; h[6] = (_Float16)f1.z; h[7] = (_Float16)f1.w;
    *(half8*)(Xh + (size_t)m * DINc + k8 * 8) = h;
}

// ---------------- generic 3-matrix transpose + convert: Mt[g][n][k] = (f16) M_g[k][n] ----------------
__global__ __launch_bounds__(256) void k_cvtW(const float* __restrict__ M0, const float* __restrict__ M1,
                                              const float* __restrict__ M2, _Float16* __restrict__ Mt) {
    __shared__ float tile[64][65];
    int g = blockIdx.z;
    const float* W = (g == 0) ? M0 : ((g == 1) ? M1 : M2);
    int n0 = blockIdx.x * 64, k0 = blockIdx.y * 64;
    int c = threadIdx.x & 63, r4 = threadIdx.x >> 6;
#pragma unroll
    for (int i = 0; i < 16; ++i) {
        int k = r4 + i * 4;
        tile[k][c] = W[(size_t)(k0 + k) * D_ + n0 + c];
    }
    __syncthreads();
    _Float16* out = Mt + (size_t)g * D_ * DINc;
#pragma unroll
    for (int i = 0; i < 16; ++i) {
        int n = r4 + i * 4;
        out[(size_t)(n0 + n) * DINc + k0 + c] = (_Float16)tile[c][n];
    }
}

// ---------------- mask transpose: maskT[t][b] = (float) mask[b][t] ----------------
__global__ __launch_bounds__(256) void k_cvtM(const int* __restrict__ mask, float* __restrict__ maskT) {
    int idx = blockIdx.x * 256 + threadIdx.x;   // 32768
    int t = idx >> 6, b = idx & 63;
    maskT[idx] = (float)mask[(size_t)b * T_ + t];
}

// ---- input projections: xprojT[g][t][n][b] = (Xh[m] @ W_g)[n] + b_g[n], m=t*64+b (f16) ----
__global__ __launch_bounds__(256) void k_gemm(const _Float16* __restrict__ Xh, const _Float16* __restrict__ Wt,
                                              const float* __restrict__ bz, const float* __restrict__ br,
                                              const float* __restrict__ bh, _Float16* __restrict__ xprojT) {
    __shared__ _Float16 As[128 * 32];
    __shared__ _Float16 Bs[128 * 32];
    int g = blockIdx.z;
    const _Float16* Wg = Wt + (size_t)g * 512 * 512;
    const float* bias = (g == 0) ? bz : ((g == 1) ? br : bh);
    _Float16* out = xprojT + (size_t)g * 16777216;
    int mb = blockIdx.x * 128, nb = blockIdx.y * 128;
    int tid = threadIdx.x, l = tid & 63, w = tid >> 6;
    int wr = w >> 1, wc = w & 1;
    int lr = l & 15, lg = l >> 4;

    floatx4 acc[4][4] = {};

    int ga0 = tid, ga1 = tid + 256;
    int ra0 = ga0 >> 2, ca0 = (ga0 & 3) * 8;
    int ra1 = ga1 >> 2, ca1 = (ga1 & 3) * 8;

    uint4 pa0, pa1, pb0, pb1;
    pa0 = *(const uint4*)(Xh + (size_t)(mb + ra0) * 512 + ca0);
    pa1 = *(const uint4*)(Xh + (size_t)(mb + ra1) * 512 + ca1);
    pb0 = *(const uint4*)(Wg + (size_t)(nb + ra0) * 512 + ca0);
    pb1 = *(const uint4*)(Wg + (size_t)(nb + ra1) * 512 + ca1);

    for (int kt = 0; kt < 16; ++kt) {
        __syncthreads();
        *(uint4*)(&As[ga0 * 8]) = pa0;
        *(uint4*)(&As[ga1 * 8]) = pa1;
        *(uint4*)(&Bs[ga0 * 8]) = pb0;
        *(uint4*)(&Bs[ga1 * 8]) = pb1;
        __syncthreads();
        if (kt < 15) {
            int kb = (kt + 1) * 32;
            pa0 = *(const uint4*)(Xh + (size_t)(mb + ra0) * 512 + kb + ca0);
            pa1 = *(const uint4*)(Xh + (size_t)(mb + ra1) * 512 + kb + ca1);
            pb0 = *(const uint4*)(Wg + (size_t)(nb + ra0) * 512 + kb + ca0);
            pb1 = *(const uint4*)(Wg + (size_t)(nb + ra1) * 512 + kb + ca1);
        }
        half8 af[4], bf[4];
#pragma unroll
        for (int mi = 0; mi < 4; mi++) af[mi] = *(const half8*)(&As[(wr * 64 + mi * 16 + lr) * 32 + lg * 8]);
#pragma unroll
        for (int ni = 0; ni < 4; ni++) bf[ni] = *(const half8*)(&Bs[(wc * 64 + ni * 16 + lr) * 32 + lg * 8]);
#pragma unroll
        for (int mi = 0; mi < 4; mi++)
#pragma unroll
            for (int ni = 0; ni < 4; ni++)
                acc[mi][ni] = __builtin_amdgcn_mfma_f32_16x16x32_f16(af[mi], bf[ni], acc[mi][ni], 0, 0, 0);
    }

#pragma unroll
    for (int ni = 0; ni < 4; ni++) {
        int col = nb + wc * 64 + ni * 16 + lr;
        float bv = bias[col];
#pragma unroll
        for (int mi = 0; mi < 4; mi++) {
            int row = mb + wr * 64 + mi * 16 + lg * 4;
            int tt = row >> 6, bb = row & 63;
            half4 hv;
#pragma unroll
            for (int i = 0; i < 4; i++) hv[i] = (_Float16)(acc[mi][ni][i] + bv);
            *(half4*)(out + (size_t)tt * 32768 + (size_t)col * 64 + bb) = hv;
        }
    }
}

// -------- agent-scope (device-coherent) primitives — PROVEN path (R2/R6/R9) --------
__device__ __forceinline__ void st_agent(unsigned long long* p, unsigned long long v) {
    __hip_atomic_store(p, v, __ATOMIC_RELAXED, __HIP_MEMORY_SCOPE_AGENT);
}
__device__ __forceinline__ unsigned ld_flag(const unsigned* p) {
    return __hip_atomic_load(p, __ATOMIC_RELAXED, __HIP_MEMORY_SCOPE_AGENT);
}
__device__ __forceinline__ void st_flag(unsigned* p, unsigned v) {
    __hip_atomic_store(p, v, __ATOMIC_RELAXED, __HIP_MEMORY_SCOPE_AGENT);
}
__device__ __forceinline__ uintx4 ld16_agent(const void* p) {
    uintx4 r;
    asm volatile("global_load_dwordx4 %0, %1, off sc0 sc1" : "=v"(r) : "v"(p) : "memory");
    return r;
}

// pack 4 fp32 (4 rows, 1 col) -> 8B row-major unit (1 row, 4 cols), 2-round butterfly (R6-proven)
__device__ __forceinline__ unsigned long long pack_quad(const float v4[4], int lr) {
    unsigned long long unit = 0;
    int j = lr & 3;
#pragma unroll
    for (int i = 0; i < 4; i++) {
        _Float16 hv = (_Float16)v4[i];
        unsigned int v = (unsigned int)__builtin_bit_cast(unsigned short, hv);
        unsigned int o1 = __shfl_xor(v, 1, 64);
        unsigned int pair = (lr & 1) ? (o1 | (v << 16)) : (v | (o1 << 16));
        unsigned int q2 = __shfl_xor(pair, 2, 64);
        unsigned long long u = (lr & 2) ? ((unsigned long long)q2 | ((unsigned long long)pair << 32))
                                        : ((unsigned long long)pair | ((unsigned long long)q2 << 32));
        if (i == j) unit = u;
    }
    return unit;
}

// every-wave poll of 128 per-wave flags (lanes -> flags l and 64+l), R9-proven
__device__ __forceinline__ void poll_flags(const unsigned* f, unsigned need, int l) {
    for (;;) {
        unsigned v0 = ld_flag(f + l * 16);
        unsigned v1 = ld_flag(f + (64 + l) * 16);
        if (__all(v0 >= need && v1 >= need)) break;
    }
    SCB();
}

// ---------------- recurrent scan: 16 WGs x 512 threads, ONE rendezvous per step ----------------
// Each WG gathers full hm (R9 path), then computes the FULL r vector locally
// (streaming Ur from XCD-L2 as MFMA B-frags), forms r*hm in place in staging LDS,
// and runs the Uh matmul for its own 32 columns (Uh frags in registers).
__global__ __launch_bounds__(512) void k_scan(const _Float16* __restrict__ Ut,      // [3][n][k] f16
                                              const float* __restrict__ maskT,
                                              const _Float16* __restrict__ xprojT,
                                              unsigned long long* __restrict__ hbuf,   // [2][64][128] u64
                                              unsigned* __restrict__ fh,
                                              float* __restrict__ out) {
    __shared__ __align__(16) _Float16 UzL[JS * 512];        // 32KB: Uz own cols [n 32][k 512] swizzled
    __shared__ __align__(16) _Float16 Stg[64 * 512];        // 64KB: hm staging -> r*hm in place
    char* StgB = (char*)Stg;
    int tid = threadIdx.x, l = tid & 63, w = tid >> 6;
    int lr = l & 15, lg = l >> 4;
    int mz = w >> 1, nz = w & 1;              // own-col output tile (z/hh): M-tile mz, N-tile nz
    int slot = blockIdx.x;
    int jsb = slot * JS;
    const int fidx = slot * 8 + w;            // per-wave flag (128 total)

    // ---- stage Uz (own 32 cols) into LDS, swizzled ----
    for (int c = tid; c < JS * 64; c += 512) {     // 32 n x 64 16B-chunks
        int n   = c >> 6;
        int k16 = c & 63;
        uintx4 v = *(const uintx4*)(Ut + (size_t)(jsb + n) * 512 + k16 * 8);
        *(uintx4*)((char*)UzL + n * 1024 + ((k16 * 16) ^ ((n & 7) << 4))) = v;
    }
    // ---- preload U_h fragments (own-col tile) into registers (static across t) ----
    half8 uhf[16];
    {
        const _Float16* UtH = Ut + (size_t)2 * 262144;
        int ncol = jsb + nz * 16 + lr;
#pragma unroll
        for (int j = 0; j < 16; j++)
            uhf[j] = *(const half8*)(UtH + (size_t)ncol * 512 + j * 32 + lg * 8);
    }
    __syncthreads();

    const int swz = (lr & 7) << 4;
    const char* SA0 = StgB + (0  + lr) * 1024;   // A-frag row bases (staging, all 4 M-tiles)
    const char* SA1 = StgB + (16 + lr) * 1024;
    const char* SA2 = StgB + (32 + lr) * 1024;
    const char* SA3 = StgB + (48 + lr) * 1024;
    const char* SAz = StgB + (mz * 16 + lr) * 1024;   // own-tile A base (z and hh)
    const char* UBz = (const char*)UzL + (nz * 16 + lr) * 1024;
    const _Float16* urB0 = Ut + 262144 + (size_t)(w * 64 +  0 + lr) * 512 + lg * 8;  // Ur B-frag bases
    const _Float16* urB1 = Ut + 262144 + (size_t)(w * 64 + 16 + lr) * 512 + lg * 8;
    const _Float16* urB2 = Ut + 262144 + (size_t)(w * 64 + 32 + lr) * 512 + lg * 8;
    const _Float16* urB3 = Ut + 262144 + (size_t)(w * 64 + 48 + lr) * 512 + lg * 8;

    int row0 = mz * 16 + lg * 4;              // this thread's 4 C-rows (batch)
    int colg = jsb + nz * 16 + lr;            // this thread's C-col (global hidden index)

    float h4[4]  = {0.f, 0.f, 0.f, 0.f};
    float hm4[4] = {0.f, 0.f, 0.f, 0.f};

    const int punit = (mz * 16 + lg * 4 + (lr & 3)) * 128 + ((jsb + nz * 16) >> 2) + ((lr >> 2) & 3);

    const _Float16* xzB = xprojT + (size_t)colg * 64;
    const _Float16* xhB = xzB + (size_t)2 * 16777216;
    const _Float16* xrG = xprojT + (size_t)16777216;   // full r-gate projections

    // ---------------- step 0: hm = 0, pure local (r irrelevant) ----------------
    {
        half4 xz0 = *(const half4*)(xzB + row0);
        half4 xh0 = *(const half4*)(xhB + row0);
        float4 m0 = *(const float4*)(maskT + row0);
#pragma unroll
        for (int i = 0; i < 4; i++) {
            float z  = __builtin_amdgcn_rcpf(1.f + __expf(-(float)xz0[i]));
            float hh = tanhf((float)xh0[i]);
            h4[i]  = (1.f - z) * hh;
            hm4[i] = ((float)m0[i]) * h4[i];
        }
        st_agent(hbuf + punit, pack_quad(hm4, lr));   // parity 0
        WAITV(0);
        if (l == 0) st_flag(fh + fidx * 16, 1u);
    }

    for (int t = 1; t < T_; ++t) {
        const char* hmG = (const char*)(hbuf + ((t - 1) & 1) * 8192);
        unsigned long long* hW = hbuf + (t & 1) * 8192;

        // prefetch own-col x's + mask (fly during the flag wait)
        half4 xzp = *(const half4*)(xzB + (size_t)t * 32768 + row0);
        half4 xhp = *(const half4*)(xhB + (size_t)t * 32768 + row0);
        float4 mv = *(const float4*)(maskT + (size_t)t * 64 + row0);

        // ================= single rendezvous: gather hm_{t-1} =================
        __syncthreads();                 // all waves done reading Stg (prev step's hh)
        poll_flags(fh, (unsigned)t, l);
        {
            uintx4 gg[8];
#pragma unroll
            for (int it = 0; it < 8; ++it)
                gg[it] = ld16_agent(hmG + (w * 8 + it) * 1024 + l * 16);
            WAITV(4); SCB();
#pragma unroll
            for (int it = 0; it < 4; ++it)
                *(uintx4*)(StgB + (w * 8 + it) * 1024 + ((l * 16) ^ (it << 4))) = gg[it];
            WAITV(0); SCB();
#pragma unroll
            for (int it = 4; it < 8; ++it)
                *(uintx4*)(StgB + (w * 8 + it) * 1024 + ((l * 16) ^ (it << 4))) = gg[it];
        }
        __syncthreads();

        // ====== full-r matmul (64x512, this wave: 4 M-tiles x 4 N-tiles) + own-col z ======
        floatx4 racc[4][4] = {};
        floatx4 zacc = {};
        half8 bb0 = *(const half8*)(urB0);
        half8 bb1 = *(const half8*)(urB1);
        half8 bb2 = *(const half8*)(urB2);
        half8 bb3 = *(const half8*)(urB3);
#pragma unroll
        for (int j = 0; j < 16; j++) {
            int aoff = (j * 64 + lg * 16) ^ swz;
            half8 a0 = *(const half8*)(SA0 + aoff);
            half8 a1 = *(const half8*)(SA1 + aoff);
            half8 a2 = *(const half8*)(SA2 + aoff);
            half8 a3 = *(const half8*)(SA3 + aoff);
            half8 az = *(const half8*)(SAz + aoff);
            half8 bz = *(const half8*)(UBz + aoff);
            half8 nb0, nb1, nb2, nb3;
            if (j < 15) {
                nb0 = *(const half8*)(urB0 + (j + 1) * 32);
                nb1 = *(const half8*)(urB1 + (j + 1) * 32);
                nb2 = *(const half8*)(urB2 + (j + 1) * 32);
                nb3 = *(const half8*)(urB3 + (j + 1) * 32);
            }
            zacc = __builtin_amdgcn_mfma_f32_16x16x32_f16(az, bz, zacc, 0, 0, 0);
            racc[0][0] = __builtin_amdgcn_mfma_f32_16x16x32_f16(a0, bb0, racc[0][0], 0, 0, 0);
            racc[1][0] = __builtin_amdgcn_mfma_f32_16x16x32_f16(a1, bb0, racc[1][0], 0, 0, 0);
            racc[2][0] = __builtin_amdgcn_mfma_f32_16x16x32_f16(a2, bb0, racc[2][0], 0, 0, 0);
            racc[3][0] = __builtin_amdgcn_mfma_f32_16x16x32_f16(a3, bb0, racc[3][0], 0, 0, 0);
            racc[0][1] = __builtin_amdgcn_mfma_f32_16x16x32_f16(a0, bb1, racc[0][1], 0, 0, 0);
            racc[1][1] = __builtin_amdgcn_mfma_f32_16x16x32_f16(a1, bb1, racc[1][1], 0, 0, 0);
            racc[2][1] = __builtin_amdgcn_mfma_f32_16x16x32_f16(a2, bb1, racc[2][1], 0, 0, 0);
            racc[3][1] = __builtin_amdgcn_mfma_f32_16x16x32_f16(a3, bb1, racc[3][1], 0, 0, 0);
            racc[0][2] = __builtin_amdgcn_mfma_f32_16x16x32_f16(a0, bb2, racc[0][2], 0, 0, 0);
            racc[1][2] = __builtin_amdgcn_mfma_f32_16x16x32_f16(a1, bb2, racc[1][2], 0, 0, 0);
            racc[2][2] = __builtin_amdgcn_mfma_f32_16x16x32_f16(a2, bb2, racc[2][2], 0, 0, 0);
            racc[3][2] = __builtin_amdgcn_mfma_f32_16x16x32_f16(a3, bb2, racc[3][2], 0, 0, 0);
            racc[0][3] = __builtin_amdgcn_mfma_f32_16x16x32_f16(a0, bb3, racc[0][3], 0, 0, 0);
            racc[1][3] = __builtin_amdgcn_mfma_f32_16x16x32_f16(a1, bb3, racc[1][3], 0, 0, 0);
            racc[2][3] = __builtin_amdgcn_mfma_f32_16x16x32_f16(a2, bb3, racc[2][3], 0, 0, 0);
            racc[3][3] = __builtin_amdgcn_mfma_f32_16x16x32_f16(a3, bb3, racc[3][3], 0, 0, 0);
            if (j < 15) { bb0 = nb0; bb1 = nb1; bb2 = nb2; bb3 = nb3; }
        }
        float z4[4];
#pragma unroll
        for (int i = 0; i < 4; i++)
            z4[i] = __builtin_amdgcn_rcpf(1.f + __expf(-((float)xzp[i] + zacc[i])));

        // ====== sigmoid(r) in place (needs full xr slice, L3-resident) ======
#pragma unroll
        for (int m = 0; m < 4; m++)
#pragma unroll
            for (int nn = 0; nn < 4; nn++) {
                half4 xr = *(const half4*)(xrG + (size_t)t * 32768 +
                                           (size_t)(w * 64 + nn * 16 + lr) * 64 + m * 16 + lg * 4);
#pragma unroll
                for (int i = 0; i < 4; i++)
                    racc[m][nn][i] = __builtin_amdgcn_rcpf(1.f + __expf(-((float)xr[i] + racc[m][nn][i])));
            }
        __syncthreads();   // all A-reads of hm complete everywhere

        // ====== r*hm in place in staging (pack to row-major units, pk-mul, write back) ======
#pragma unroll
        for (int m = 0; m < 4; m++)
#pragma unroll
            for (int nn = 0; nn < 4; nn++) {
                float tmp[4] = {racc[m][nn][0], racc[m][nn][1], racc[m][nn][2], racc[m][nn][3]};
                unsigned long long u = pack_quad(tmp, lr);
                int R  = m * 16 + lg * 4 + (lr & 3);
                int c0 = w * 64 + nn * 16 + ((lr >> 2) & 3) * 4;
                int byteoff = R * 1024 + (((c0 >> 3) * 16) ^ ((R & 7) << 4)) + ((c0 & 4) ? 8 : 0);
                half4 hmu = *(half4*)(StgB + byteoff);
                half4 ru  = __builtin_bit_cast(half4, u);
                half4 prod = ru * hmu;
                *(half4*)(StgB + byteoff) = prod;
            }
        __syncthreads();

        // ====== hh matmul (own-col tile) + state update ======
        floatx4 acch = {};
#pragma unroll
        for (int j = 0; j < 16; j++) {
            half8 ah = *(const half8*)(SAz + ((j * 64 + lg * 16) ^ swz));
            acch = __builtin_amdgcn_mfma_f32_16x16x32_f16(ah, uhf[j], acch, 0, 0, 0);
        }
#pragma unroll
        for (int i = 0; i < 4; i++) {
            float hh = tanhf((float)xhp[i] + acch[i]);
            h4[i]  = z4[i] * hm4[i] + (1.f - z4[i]) * hh;
            hm4[i] = ((float)mv[i]) * h4[i];
        }
        if (t < T_ - 1) {
            st_agent(hW + punit, pack_quad(hm4, lr));
            WAITV(0);
            if (l == 0) st_flag(fh + fidx * 16, (unsigned)(t + 1));
        }
    }

#pragma unroll
    for (int i = 0; i < 4; i++)
        out[(size_t)(row0 + i) * 512 + colg] = h4[i];
}

extern "C" void kernel_launch(void* const* d_in, const int* in_sizes, int n_in,
                              void* d_out, int out_size, void* d_ws, size_t ws_size,
                              hipStream_t stream) {
    (void)in_sizes; (void)n_in; (void)out_size; (void)ws_size;
    const float* X  = (const float*)d_in[0];
    const float* Wz = (const float*)d_in[1];
    const float* Uz = (const float*)d_in[2];
    const float* bz = (const float*)d_in[3];
    const float* Wr = (const float*)d_in[4];
    const float* Ur = (const float*)d_in[5];
    const float* br = (const float*)d_in[6];
    const float* Wh = (const float*)d_in[7];
    const float* Uh = (const float*)d_in[8];
    const float* bh = (const float*)d_in[9];
    const int* mask = (const int*)d_in[10];
    float* out = (float*)d_out;

    char* ws = (char*)d_ws;
    unsigned* fh = (unsigned*)ws;                                    // 8KB: 128 per-wave flags, 64B stride
    unsigned long long* hbuf  = (unsigned long long*)(ws + 16384);              // 128KB [2][64][128]
    _Float16* Xh     = (_Float16*)(ws + 16384 + 2 * 131072);                    // 32MB
    _Float16* Wt     = (_Float16*)(ws + 16384 + 2 * 131072 + 33554432);         // 1.5MB
    _Float16* Ut     = (_Float16*)(ws + 16384 + 2 * 131072 + 33554432 + 1572864);           // 1.5MB
    _Float16* xprojT = (_Float16*)(ws + 16384 + 2 * 131072 + 33554432 + 2 * 1572864);       // 96MB
    float*    maskT  = (float*)(ws + 16384 + 2 * 131072 + 33554432 + 2 * 1572864 + 100663296); // 128KB

    hipMemsetAsync(ws, 0, 16384, stream);
    hipLaunchKernelGGL(k_cvtX, dim3(8192), dim3(256), 0, stream, X, Xh);
    hipLaunchKernelGGL(k_cvtW, dim3(8, 8, 3), dim3(256), 0, stream, Wz, Wr, Wh, Wt);
    hipLaunchKernelGGL(k_cvtW, dim3(8, 8, 3), dim3(256), 0, stream, Uz, Ur, Uh, Ut);
    hipLaunchKernelGGL(k_cvtM, dim3(128), dim3(256), 0, stream, mask, maskT);
    hipLaunchKernelGGL(k_gemm, dim3(256, 4, 3), dim3(256), 0, stream, Xh, Wt, bz, br, bh, xprojT);
    hipLaunchKernelGGL(k_scan, dim3(NWG), dim3(512), 0, stream, Ut, maskT, xprojT,
                       hbuf, fh, out);
}

// Round 12
// 4255.902 us; speedup vs baseline: 3.4235x; 3.4235x over previous
//
#include <hip/hip_runtime.h>
#include <hip/hip_fp16.h>

#define B_   64
#define T_   512
#define DINc 512
#define D_   512
#define NWG  16
#define JS   32   // output columns per workgroup in scan

typedef _Float16 half8 __attribute__((ext_vector_type(8)));
typedef _Float16 half4 __attribute__((ext_vector_type(4)));
typedef float   floatx4 __attribute__((ext_vector_type(4)));
typedef unsigned uintx4 __attribute__((ext_vector_type(4)));

#define WAITV(N) asm volatile("s_waitcnt vmcnt(" #N ")" ::: "memory")
#define SCB()    __builtin_amdgcn_sched_barrier(0)

// ---------------- X convert + transpose: Xh[m][k] = (f16) X[b][t][k], m = t*64+b ----------------
__global__ __launch_bounds__(256) void k_cvtX(const float* __restrict__ X, _Float16* __restrict__ Xh) {
    int idx = blockIdx.x * 256 + threadIdx.x;
    int m  = idx >> 6;
    int k8 = idx & 63;
    int b = m & 63, t = m >> 6;
    const float* src = X + ((size_t)(b * T_ + t)) * DINc + k8 * 8;
    float4 f0 = *(const float4*)(src);
    float4 f1 = *(const float4*)(src + 4);
    half8 h;
    h[0] = (_Float16)f0.x; h[1] = (_Float16)f0.y; h[2] = (_Float16)f0.z; h[3] = (_Float16)f0.w;
    h[4] = (_Float16)f1.x; h[5] = (_Float16)f1.y; h[6] = (_Float16)f1.z; h[7] = (_Float16)f1.w;
    *(half8*)(Xh + (size_t)m * DINc + k8 * 8) = h;
}

// ---------------- generic 3-matrix transpose + convert: Mt[g][n][k] = (f16) M_g[k][n] ----------------
__global__ __launch_bounds__(256) void k_cvtW(const float* __restrict__ M0, const float* __restrict__ M1,
                                              const float* __restrict__ M2, _Float16* __restrict__ Mt) {
    __shared__ float tile[64][65];
    int g = blockIdx.z;
    const float* W = (g == 0) ? M0 : ((g == 1) ? M1 : M2);
    int n0 = blockIdx.x * 64, k0 = blockIdx.y * 64;
    int c = threadIdx.x & 63, r4 = threadIdx.x >> 6;
#pragma unroll
    for (int i = 0; i < 16; ++i) {
        int k = r4 + i * 4;
        tile[k][c] = W[(size_t)(k0 + k) * D_ + n0 + c];
    }
    __syncthreads();
    _Float16* out = Mt + (size_t)g * D_ * DINc;
#pragma unroll
    for (int i = 0; i < 16; ++i) {
        int n = r4 + i * 4;
        out[(size_t)(n0 + n) * DINc + k0 + c] = (_Float16)tile[c][n];
    }
}

// ---------------- mask transpose: maskT[t][b] = (float) mask[b][t] ----------------
__global__ __launch_bounds__(256) void k_cvtM(const int* __restrict__ mask, float* __restrict__ maskT) {
    int idx = blockIdx.x * 256 + threadIdx.x;   // 32768
    int t = idx >> 6, b = idx & 63;
    maskT[idx] = (float)mask[(size_t)b * T_ + t];
}

// ---- input projections: xprojT[g][t][n][b] = (Xh[m] @ W_g)[n] + b_g[n], m=t*64+b (f16) ----
__global__ __launch_bounds__(256) void k_gemm(const _Float16* __restrict__ Xh, const _Float16* __restrict__ Wt,
                                              const float* __restrict__ bz, const float* __restrict__ br,
                                              const float* __restrict__ bh, _Float16* __restrict__ xprojT) {
    __shared__ _Float16 As[128 * 32];
    __shared__ _Float16 Bs[128 * 32];
    int g = blockIdx.z;
    const _Float16* Wg = Wt + (size_t)g * 512 * 512;
    const float* bias = (g == 0) ? bz : ((g == 1) ? br : bh);
    _Float16* out = xprojT + (size_t)g * 16777216;
    int mb = blockIdx.x * 128, nb = blockIdx.y * 128;
    int tid = threadIdx.x, l = tid & 63, w = tid >> 6;
    int wr = w >> 1, wc = w & 1;
    int lr = l & 15, lg = l >> 4;

    floatx4 acc[4][4] = {};

    int ga0 = tid, ga1 = tid + 256;
    int ra0 = ga0 >> 2, ca0 = (ga0 & 3) * 8;
    int ra1 = ga1 >> 2, ca1 = (ga1 & 3) * 8;

    uint4 pa0, pa1, pb0, pb1;
    pa0 = *(const uint4*)(Xh + (size_t)(mb + ra0) * 512 + ca0);
    pa1 = *(const uint4*)(Xh + (size_t)(mb + ra1) * 512 + ca1);
    pb0 = *(const uint4*)(Wg + (size_t)(nb + ra0) * 512 + ca0);
    pb1 = *(const uint4*)(Wg + (size_t)(nb + ra1) * 512 + ca1);

    for (int kt = 0; kt < 16; ++kt) {
        __syncthreads();
        *(uint4*)(&As[ga0 * 8]) = pa0;
        *(uint4*)(&As[ga1 * 8]) = pa1;
        *(uint4*)(&Bs[ga0 * 8]) = pb0;
        *(uint4*)(&Bs[ga1 * 8]) = pb1;
        __syncthreads();
        if (kt < 15) {
            int kb = (kt + 1) * 32;
            pa0 = *(const uint4*)(Xh + (size_t)(mb + ra0) * 512 + kb + ca0);
            pa1 = *(const uint4*)(Xh + (size_t)(mb + ra1) * 512 + kb + ca1);
            pb0 = *(const uint4*)(Wg + (size_t)(nb + ra0) * 512 + kb + ca0);
            pb1 = *(const uint4*)(Wg + (size_t)(nb + ra1) * 512 + kb + ca1);
        }
        half8 af[4], bf[4];
#pragma unroll
        for (int mi = 0; mi < 4; mi++) af[mi] = *(const half8*)(&As[(wr * 64 + mi * 16 + lr) * 32 + lg * 8]);
#pragma unroll
        for (int ni = 0; ni < 4; ni++) bf[ni] = *(const half8*)(&Bs[(wc * 64 + ni * 16 + lr) * 32 + lg * 8]);
#pragma unroll
        for (int mi = 0; mi < 4; mi++)
#pragma unroll
            for (int ni = 0; ni < 4; ni++)
                acc[mi][ni] = __builtin_amdgcn_mfma_f32_16x16x32_f16(af[mi], bf[ni], acc[mi][ni], 0, 0, 0);
    }

#pragma unroll
    for (int ni = 0; ni < 4; ni++) {
        int col = nb + wc * 64 + ni * 16 + lr;
        float bv = bias[col];
#pragma unroll
        for (int mi = 0; mi < 4; mi++) {
            int row = mb + wr * 64 + mi * 16 + lg * 4;
            int tt = row >> 6, bb = row & 63;
            half4 hv;
#pragma unroll
            for (int i = 0; i < 4; i++) hv[i] = (_Float16)(acc[mi][ni][i] + bv);
            *(half4*)(out + (size_t)tt * 32768 + (size_t)col * 64 + bb) = hv;
        }
    }
}

// -------- agent-scope (device-coherent) primitives — PROVEN path (R2/R6/R8/R9) --------
__device__ __forceinline__ void st_agent(unsigned long long* p, unsigned long long v) {
    __hip_atomic_store(p, v, __ATOMIC_RELAXED, __HIP_MEMORY_SCOPE_AGENT);
}
__device__ __forceinline__ uintx4 ld16_agent(const void* p) {
    uintx4 r;
    asm volatile("global_load_dwordx4 %0, %1, off sc0 sc1" : "=v"(r) : "v"(p) : "memory");
    return r;
}
// chunk (16B = 2x 8B publish units) is valid iff neither u64 is the 0xFF.. sentinel
__device__ __forceinline__ bool chunk_valid(uintx4 v) {
    return ((v[0] & v[1]) != 0xFFFFFFFFu) && ((v[2] & v[3]) != 0xFFFFFFFFu);
}

// pack 4 fp32 (4 rows, 1 col) -> 8B row-major unit (1 row, 4 cols), 2-round butterfly (R6-proven)
__device__ __forceinline__ unsigned long long pack_quad(const float v4[4], int lr) {
    unsigned long long unit = 0;
    int j = lr & 3;
#pragma unroll
    for (int i = 0; i < 4; i++) {
        _Float16 hv = (_Float16)v4[i];
        unsigned int v = (unsigned int)__builtin_bit_cast(unsigned short, hv);
        unsigned int o1 = __shfl_xor(v, 1, 64);
        unsigned int pair = (lr & 1) ? (o1 | (v << 16)) : (v | (o1 << 16));
        unsigned int q2 = __shfl_xor(pair, 2, 64);
        unsigned long long u = (lr & 2) ? ((unsigned long long)q2 | ((unsigned long long)pair << 32))
                                        : ((unsigned long long)pair | ((unsigned long long)q2 << 32));
        if (i == j) unit = u;
    }
    return unit;
}

// ---------------- recurrent scan: 16 WGs x 512 threads, sentinel-signalled exchange ----------------
// Producers publish with ONE relaxed 8B store (no drain, no flag). Consumers gather with
// PARTIAL retry: re-load only still-poisoned 16B chunks. Poison schedule = R8 (proven):
//   t ph1: hm_{t-1} gathered  ==> all WGs past ph2 of t-1 ==> poison rhbuf[(t-1)&1]
//   t ph2: rh_t gathered      ==> all WGs past ph1 of t   ==> poison hbuf[(t-1)&1]
// Ordering of poison-before-republish is enforced by the gather loops' vmcnt(0) drains.
__global__ __launch_bounds__(512) void k_scan(const _Float16* __restrict__ Ut,      // [3][n][k] f16
                                              const float* __restrict__ maskT,
                                              const _Float16* __restrict__ xprojT,
                                              unsigned long long* __restrict__ hbuf,   // [2][64][128] u64
                                              unsigned long long* __restrict__ rhbuf,  // [2][64][128] u64
                                              float* __restrict__ out) {
    __shared__ __align__(16) _Float16 Ulds[2 * JS * 512];   // 64KB: Uz,Ur [n][k] swizzled
    __shared__ __align__(16) _Float16 Stg[64 * 512];        // 64KB: exchange staging, swizzled
    char* StgB = (char*)Stg;
    int tid = threadIdx.x, l = tid & 63, w = tid >> 6;
    int lr = l & 15, lg = l >> 4;
    int mt = w >> 1, nt = w & 1;              // wave's (M,N) 16x16 tile
    int slot = blockIdx.x;
    int jsb = slot * JS;

    // ---- stage Uz, Ur into LDS (already transposed f16; add XOR swizzle) ----
    for (int c = tid; c < 2 * JS * 64; c += 512) {     // 16B chunks: 2 gates x 32 n x 64 chunks
        int g  = c >> 11;
        int n  = (c >> 6) & 31;
        int k16 = c & 63;
        uintx4 v = *(const uintx4*)(Ut + (size_t)g * 262144 + (size_t)(jsb + n) * 512 + k16 * 8);
        *(uintx4*)((char*)Ulds + g * 32768 + n * 1024 + ((k16 * 16) ^ ((n & 7) << 4))) = v;
    }
    // ---- preload U_h fragments into registers (static across t) ----
    half8 uhf[16];
    {
        const _Float16* UtH = Ut + (size_t)2 * 262144;
        int ncol = jsb + nt * 16 + lr;
#pragma unroll
        for (int j = 0; j < 16; j++)
            uhf[j] = *(const half8*)(UtH + (size_t)ncol * 512 + j * 32 + lg * 8);
    }
    __syncthreads();

    const char* UB = (const char*)Ulds + (nt * 16 + lr) * 1024;  // B-row base for Uz (Ur at +32KB)
    const int swz = (lr & 7) << 4;

    int row0 = mt * 16 + lg * 4;              // this thread's 4 C-rows (batch)
    int colg = jsb + nt * 16 + lr;            // this thread's C-col (global hidden index)

    float h4[4]  = {0.f, 0.f, 0.f, 0.f};
    float hm4[4] = {0.f, 0.f, 0.f, 0.f};

    const int punit = (mt * 16 + lg * 4 + (lr & 3)) * 128 + ((jsb + nt * 16) >> 2) + ((lr >> 2) & 3);
    const char* SB = StgB + (mt * 16 + lr) * 1024;    // A-frag row base in staging

    const _Float16* xzB = xprojT + (size_t)colg * 64 + row0;
    const _Float16* xrB = xzB + (size_t)16777216;
    const _Float16* xhB = xrB + (size_t)16777216;

    // ---------------- step 0: hm = 0, pure local ----------------
    {
        half4 xz0 = *(const half4*)(xzB);
        half4 xh0 = *(const half4*)(xhB);
        float4 m0 = *(const float4*)(maskT + row0);
#pragma unroll
        for (int i = 0; i < 4; i++) {
            float z  = __builtin_amdgcn_rcpf(1.f + __expf(-(float)xz0[i]));
            float hh = tanhf((float)xh0[i]);
            h4[i]  = (1.f - z) * hh;
            hm4[i] = ((float)m0[i]) * h4[i];
        }
        st_agent(hbuf + punit, pack_quad(hm4, lr));   // parity 0; fire-and-forget
    }

    for (int t = 1; t < T_; ++t) {
        const char* hmG = (const char*)(hbuf + ((t - 1) & 1) * 8192);
        unsigned long long* rhPsn = rhbuf + ((t - 1) & 1) * 8192;   // poison target, ph1
        unsigned long long* hPsn  = hbuf  + ((t - 1) & 1) * 8192;   // poison target, ph2
        unsigned long long* rhW   = rhbuf + (t & 1) * 8192;
        unsigned long long* hW    = hbuf  + (t & 1) * 8192;
        const char* rhG = (const char*)rhW;

        // issue this step's x loads early (drained by first gather WAITV)
        half4 xzp = *(const half4*)(xzB + (size_t)t * 32768);
        half4 xrp = *(const half4*)(xrB + (size_t)t * 32768);
        half4 xhp = *(const half4*)(xhB + (size_t)t * 32768);
        float4 mv = *(const float4*)(maskT + (size_t)t * 64 + row0);

        // ================= phase 1: gather hm (partial-retry), r then z =================
        uintx4 gg[8];
        {
            unsigned vmask = 0;
#pragma unroll
            for (int it = 0; it < 8; ++it)
                gg[it] = ld16_agent(hmG + (w * 8 + it) * 1024 + l * 16);
            WAITV(0); SCB();
#pragma unroll
            for (int it = 0; it < 8; ++it) if (chunk_valid(gg[it])) vmask |= 1u << it;
            while (!__all(vmask == 255u)) {
#pragma unroll
                for (int it = 0; it < 8; ++it)
                    if (!(vmask & (1u << it)))
                        gg[it] = ld16_agent(hmG + (w * 8 + it) * 1024 + l * 16);
                WAITV(0); SCB();
#pragma unroll
                for (int it = 0; it < 8; ++it) if (chunk_valid(gg[it])) vmask |= 1u << it;
            }
        }
        st_agent(rhPsn + punit, ~0ull);   // poison rh[(t-1)&1] (all WGs past ph2 of t-1)
        __syncthreads();                  // prev staging reads done everywhere in this WG
#pragma unroll
        for (int it = 0; it < 8; ++it)
            *(uintx4*)(StgB + (w * 8 + it) * 1024 + ((l * 16) ^ (it << 4))) = gg[it];
        __syncthreads();
        half8 af[16];
#pragma unroll
        for (int j = 0; j < 16; j++)
            af[j] = *(const half8*)(SB + ((j * 64 + lg * 16) ^ swz));
        // --- r first: its result gates the next rendezvous; publish ASAP (no drain) ---
        floatx4 accr = {0.f, 0.f, 0.f, 0.f};
        __builtin_amdgcn_s_setprio(1);
#pragma unroll
        for (int j = 0; j < 16; j++) {
            int boff = (j * 64 + lg * 16) ^ swz;
            half8 br8 = *(const half8*)(UB + 32768 + boff);
            accr = __builtin_amdgcn_mfma_f32_16x16x32_f16(af[j], br8, accr, 0, 0, 0);
        }
        __builtin_amdgcn_s_setprio(0);
        float rh4[4];
#pragma unroll
        for (int i = 0; i < 4; i++) {
            float rr = __builtin_amdgcn_rcpf(1.f + __expf(-((float)xrp[i] + accr[i])));
            rh4[i] = rr * hm4[i];
        }
        st_agent(rhW + punit, pack_quad(rh4, lr));   // fire-and-forget publish
        // --- z while rh propagates to peers ---
        floatx4 accz = {0.f, 0.f, 0.f, 0.f};
        __builtin_amdgcn_s_setprio(1);
#pragma unroll
        for (int j = 0; j < 16; j++) {
            int boff = (j * 64 + lg * 16) ^ swz;
            half8 bz8 = *(const half8*)(UB + boff);
            accz = __builtin_amdgcn_mfma_f32_16x16x32_f16(af[j], bz8, accz, 0, 0, 0);
        }
        __builtin_amdgcn_s_setprio(0);
        float z4[4];
#pragma unroll
        for (int i = 0; i < 4; i++)
            z4[i] = __builtin_amdgcn_rcpf(1.f + __expf(-((float)xzp[i] + accz[i])));

        // ================= phase 2: gather rh (partial-retry), candidate + update =================
        uintx4 gg2[8];
        {
            unsigned vmask = 0;
#pragma unroll
            for (int it = 0; it < 8; ++it)
                gg2[it] = ld16_agent(rhG + (w * 8 + it) * 1024 + l * 16);
            WAITV(0); SCB();
#pragma unroll
            for (int it = 0; it < 8; ++it) if (chunk_valid(gg2[it])) vmask |= 1u << it;
            while (!__all(vmask == 255u)) {
#pragma unroll
                for (int it = 0; it < 8; ++it)
                    if (!(vmask & (1u << it)))
                        gg2[it] = ld16_agent(rhG + (w * 8 + it) * 1024 + l * 16);
                WAITV(0); SCB();
#pragma unroll
                for (int it = 0; it < 8; ++it) if (chunk_valid(gg2[it])) vmask |= 1u << it;
            }
        }
        st_agent(hPsn + punit, ~0ull);   // poison h[(t-1)&1] (all WGs past ph1 of t)
        __syncthreads();
#pragma unroll
        for (int it = 0; it < 8; ++it)
            *(uintx4*)(StgB + (w * 8 + it) * 1024 + ((l * 16) ^ (it << 4))) = gg2[it];
        __syncthreads();
        half8 af2[16];
#pragma unroll
        for (int j = 0; j < 16; j++)
            af2[j] = *(const half8*)(SB + ((j * 64 + lg * 16) ^ swz));
        floatx4 acch0 = {0.f, 0.f, 0.f, 0.f}, acch1 = {0.f, 0.f, 0.f, 0.f};
        __builtin_amdgcn_s_setprio(1);
#pragma unroll
        for (int j = 0; j < 16; j += 2) {
            acch0 = __builtin_amdgcn_mfma_f32_16x16x32_f16(af2[j],     uhf[j],     acch0, 0, 0, 0);
            acch1 = __builtin_amdgcn_mfma_f32_16x16x32_f16(af2[j + 1], uhf[j + 1], acch1, 0, 0, 0);
        }
        __builtin_amdgcn_s_setprio(0);
#pragma unroll
        for (int i = 0; i < 4; i++) {
            float hh = tanhf((float)xhp[i] + acch0[i] + acch1[i]);
            h4[i]  = z4[i] * hm4[i] + (1.f - z4[i]) * hh;
            hm4[i] = ((float)mv[i]) * h4[i];
        }
        if (t < T_ - 1)
            st_agent(hW + punit, pack_quad(hm4, lr));    // fire-and-forget publish
    }

#pragma unroll
    for (int i = 0; i < 4; i++)
        out[(size_t)(row0 + i) * 512 + colg] = h4[i];
}

extern "C" void kernel_launch(void* const* d_in, const int* in_sizes, int n_in,
                              void* d_out, int out_size, void* d_ws, size_t ws_size,
                              hipStream_t stream) {
    (void)in_sizes; (void)n_in; (void)out_size; (void)ws_size;
    const float* X  = (const float*)d_in[0];
    const float* Wz = (const float*)d_in[1];
    const float* Uz = (const float*)d_in[2];
    const float* bz = (const float*)d_in[3];
    const float* Wr = (const float*)d_in[4];
    const float* Ur = (const float*)d_in[5];
    const float* br = (const float*)d_in[6];
    const float* Wh = (const float*)d_in[7];
    const float* Uh = (const float*)d_in[8];
    const float* bh = (const float*)d_in[9];
    const int* mask = (const int*)d_in[10];
    float* out = (float*)d_out;

    char* ws = (char*)d_ws;
    unsigned long long* hbuf  = (unsigned long long*)(ws + 16384);              // 128KB [2][64][128]
    unsigned long long* rhbuf = (unsigned long long*)(ws + 16384 + 131072);     // 128KB
    _Float16* Xh     = (_Float16*)(ws + 16384 + 2 * 131072);                    // 32MB
    _Float16* Wt     = (_Float16*)(ws + 16384 + 2 * 131072 + 33554432);         // 1.5MB
    _Float16* Ut     = (_Float16*)(ws + 16384 + 2 * 131072 + 33554432 + 1572864);           // 1.5MB
    _Float16* xprojT = (_Float16*)(ws + 16384 + 2 * 131072 + 33554432 + 2 * 1572864);       // 96MB
    float*    maskT  = (float*)(ws + 16384 + 2 * 131072 + 33554432 + 2 * 1572864 + 100663296); // 128KB

    // pre-poison exchange region every launch (graph-replay determinism)
    hipMemsetAsync(ws + 16384, 0xFF, 2 * 131072, stream);
    hipLaunchKernelGGL(k_cvtX, dim3(8192), dim3(256), 0, stream, X, Xh);
    hipLaunchKernelGGL(k_cvtW, dim3(8, 8, 3), dim3(256), 0, stream, Wz, Wr, Wh, Wt);
    hipLaunchKernelGGL(k_cvtW, dim3(8, 8, 3), dim3(256), 0, stream, Uz, Ur, Uh, Ut);
    hipLaunchKernelGGL(k_cvtM, dim3(128), dim3(256), 0, stream, mask, maskT);
    hipLaunchKernelGGL(k_gemm, dim3(256, 4, 3), dim3(256), 0, stream, Xh, Wt, bz, br, bh, xprojT);
    hipLaunchKernelGGL(k_scan, dim3(NWG), dim3(512), 0, stream, Ut, maskT, xprojT,
                       hbuf, rhbuf, out);
}

// Round 13
// 3946.682 us; speedup vs baseline: 3.6917x; 1.0783x over previous
//
#include <hip/hip_runtime.h>
#include <hip/hip_fp16.h>

#define B_   64
#define T_   512
#define DINc 512
#define D_   512
#define NWG  16
#define JS   32   // output columns per workgroup in scan

typedef _Float16 half8 __attribute__((ext_vector_type(8)));
typedef _Float16 half4 __attribute__((ext_vector_type(4)));
typedef float   floatx4 __attribute__((ext_vector_type(4)));
typedef unsigned uintx4 __attribute__((ext_vector_type(4)));

#define WAITV(N) asm volatile("s_waitcnt vmcnt(" #N ")" ::: "memory")
#define SCB()    __builtin_amdgcn_sched_barrier(0)

// ---------------- X convert + transpose: Xh[m][k] = (f16) X[b][t][k], m = t*64+b ----------------
__global__ __launch_bounds__(256) void k_cvtX(const float* __restrict__ X, _Float16* __restrict__ Xh) {
    int idx = blockIdx.x * 256 + threadIdx.x;
    int m  = idx >> 6;
    int k8 = idx & 63;
    int b = m & 63, t = m >> 6;
    const float* src = X + ((size_t)(b * T_ + t)) * DINc + k8 * 8;
    float4 f0 = *(const float4*)(src);
    float4 f1 = *(const float4*)(src + 4);
    half8 h;
    h[0] = (_Float16)f0.x; h[1] = (_Float16)f0.y; h[2] = (_Float16)f0.z; h[3] = (_Float16)f0.w;
    h[4] = (_Float16)f1.x; h[5] = (_Float16)f1.y; h[6] = (_Float16)f1.z; h[7] = (_Float16)f1.w;
    *(half8*)(Xh + (size_t)m * DINc + k8 * 8) = h;
}

// ---------------- generic 3-matrix transpose + convert: Mt[g][n][k] = (f16) M_g[k][n] ----------------
__global__ __launch_bounds__(256) void k_cvtW(const float* __restrict__ M0, const float* __restrict__ M1,
                                              const float* __restrict__ M2, _Float16* __restrict__ Mt) {
    __shared__ float tile[64][65];
    int g = blockIdx.z;
    const float* W = (g == 0) ? M0 : ((g == 1) ? M1 : M2);
    int n0 = blockIdx.x * 64, k0 = blockIdx.y * 64;
    int c = threadIdx.x & 63, r4 = threadIdx.x >> 6;
#pragma unroll
    for (int i = 0; i < 16; ++i) {
        int k = r4 + i * 4;
        tile[k][c] = W[(size_t)(k0 + k) * D_ + n0 + c];
    }
    __syncthreads();
    _Float16* out = Mt + (size_t)g * D_ * DINc;
#pragma unroll
    for (int i = 0; i < 16; ++i) {
        int n = r4 + i * 4;
        out[(size_t)(n0 + n) * DINc + k0 + c] = (_Float16)tile[c][n];
    }
}

// ---------------- mask transpose: maskT[t][b] = (float) mask[b][t] ----------------
__global__ __launch_bounds__(256) void k_cvtM(const int* __restrict__ mask, float* __restrict__ maskT) {
    int idx = blockIdx.x * 256 + threadIdx.x;   // 32768
    int t = idx >> 6, b = idx & 63;
    maskT[idx] = (float)mask[(size_t)b * T_ + t];
}

// ---- input projections: xprojT[g][t][n][b] = (Xh[m] @ W_g)[n] + b_g[n], m=t*64+b (f16) ----
__global__ __launch_bounds__(256) void k_gemm(const _Float16* __restrict__ Xh, const _Float16* __restrict__ Wt,
                                              const float* __restrict__ bz, const float* __restrict__ br,
                                              const float* __restrict__ bh, _Float16* __restrict__ xprojT) {
    __shared__ _Float16 As[128 * 32];
    __shared__ _Float16 Bs[128 * 32];
    int g = blockIdx.z;
    const _Float16* Wg = Wt + (size_t)g * 512 * 512;
    const float* bias = (g == 0) ? bz : ((g == 1) ? br : bh);
    _Float16* out = xprojT + (size_t)g * 16777216;
    int mb = blockIdx.x * 128, nb = blockIdx.y * 128;
    int tid = threadIdx.x, l = tid & 63, w = tid >> 6;
    int wr = w >> 1, wc = w & 1;
    int lr = l & 15, lg = l >> 4;

    floatx4 acc[4][4] = {};

    int ga0 = tid, ga1 = tid + 256;
    int ra0 = ga0 >> 2, ca0 = (ga0 & 3) * 8;
    int ra1 = ga1 >> 2, ca1 = (ga1 & 3) * 8;

    uint4 pa0, pa1, pb0, pb1;
    pa0 = *(const uint4*)(Xh + (size_t)(mb + ra0) * 512 + ca0);
    pa1 = *(const uint4*)(Xh + (size_t)(mb + ra1) * 512 + ca1);
    pb0 = *(const uint4*)(Wg + (size_t)(nb + ra0) * 512 + ca0);
    pb1 = *(const uint4*)(Wg + (size_t)(nb + ra1) * 512 + ca1);

    for (int kt = 0; kt < 16; ++kt) {
        __syncthreads();
        *(uint4*)(&As[ga0 * 8]) = pa0;
        *(uint4*)(&As[ga1 * 8]) = pa1;
        *(uint4*)(&Bs[ga0 * 8]) = pb0;
        *(uint4*)(&Bs[ga1 * 8]) = pb1;
        __syncthreads();
        if (kt < 15) {
            int kb = (kt + 1) * 32;
            pa0 = *(const uint4*)(Xh + (size_t)(mb + ra0) * 512 + kb + ca0);
            pa1 = *(const uint4*)(Xh + (size_t)(mb + ra1) * 512 + kb + ca1);
            pb0 = *(const uint4*)(Wg + (size_t)(nb + ra0) * 512 + kb + ca0);
            pb1 = *(const uint4*)(Wg + (size_t)(nb + ra1) * 512 + kb + ca1);
        }
        half8 af[4], bf[4];
#pragma unroll
        for (int mi = 0; mi < 4; mi++) af[mi] = *(const half8*)(&As[(wr * 64 + mi * 16 + lr) * 32 + lg * 8]);
#pragma unroll
        for (int ni = 0; ni < 4; ni++) bf[ni] = *(const half8*)(&Bs[(wc * 64 + ni * 16 + lr) * 32 + lg * 8]);
#pragma unroll
        for (int mi = 0; mi < 4; mi++)
#pragma unroll
            for (int ni = 0; ni < 4; ni++)
                acc[mi][ni] = __builtin_amdgcn_mfma_f32_16x16x32_f16(af[mi], bf[ni], acc[mi][ni], 0, 0, 0);
    }

#pragma unroll
    for (int ni = 0; ni < 4; ni++) {
        int col = nb + wc * 64 + ni * 16 + lr;
        float bv = bias[col];
#pragma unroll
        for (int mi = 0; mi < 4; mi++) {
            int row = mb + wr * 64 + mi * 16 + lg * 4;
            int tt = row >> 6, bb = row & 63;
            half4 hv;
#pragma unroll
            for (int i = 0; i < 4; i++) hv[i] = (_Float16)(acc[mi][ni][i] + bv);
            *(half4*)(out + (size_t)tt * 32768 + (size_t)col * 64 + bb) = hv;
        }
    }
}

// -------- agent-scope (device-coherent) primitives — PROVEN path (R2/R6/R9/R12) --------
__device__ __forceinline__ void st_agent(unsigned long long* p, unsigned long long v) {
    __hip_atomic_store(p, v, __ATOMIC_RELAXED, __HIP_MEMORY_SCOPE_AGENT);
}
__device__ __forceinline__ unsigned ld_flag(const unsigned* p) {
    return __hip_atomic_load(p, __ATOMIC_RELAXED, __HIP_MEMORY_SCOPE_AGENT);
}
__device__ __forceinline__ void st_flag(unsigned* p, unsigned v) {
    __hip_atomic_store(p, v, __ATOMIC_RELAXED, __HIP_MEMORY_SCOPE_AGENT);
}
__device__ __forceinline__ uintx4 ld16_agent(const void* p) {
    uintx4 r;
    asm volatile("global_load_dwordx4 %0, %1, off sc0 sc1" : "=v"(r) : "v"(p) : "memory");
    return r;
}
// chunk (16B = 2x 8B publish units) valid iff neither u64 is the 0xFF.. sentinel
__device__ __forceinline__ bool chunk_valid(uintx4 v) {
    return ((v[0] & v[1]) != 0xFFFFFFFFu) && ((v[2] & v[3]) != 0xFFFFFFFFu);
}

// pack 4 fp32 (4 rows, 1 col) -> 8B row-major unit (1 row, 4 cols), 2-round butterfly (R6-proven)
__device__ __forceinline__ unsigned long long pack_quad(const float v4[4], int lr) {
    unsigned long long unit = 0;
    int j = lr & 3;
#pragma unroll
    for (int i = 0; i < 4; i++) {
        _Float16 hv = (_Float16)v4[i];
        unsigned int v = (unsigned int)__builtin_bit_cast(unsigned short, hv);
        unsigned int o1 = __shfl_xor(v, 1, 64);
        unsigned int pair = (lr & 1) ? (o1 | (v << 16)) : (v | (o1 << 16));
        unsigned int q2 = __shfl_xor(pair, 2, 64);
        unsigned long long u = (lr & 2) ? ((unsigned long long)q2 | ((unsigned long long)pair << 32))
                                        : ((unsigned long long)pair | ((unsigned long long)q2 << 32));
        if (i == j) unit = u;
    }
    return unit;
}

// every-wave poll of 128 per-wave flags (lanes -> flags l and 64+l), R9-proven
__device__ __forceinline__ void poll_flags(const unsigned* f, unsigned need, int l) {
    for (;;) {
        unsigned v0 = ld_flag(f + l * 16);
        unsigned v1 = ld_flag(f + (64 + l) * 16);
        if (__all(v0 >= need && v1 >= need)) break;
    }
    SCB();
}

// ---------------- recurrent scan: 16 WGs x 512 threads, each owns JS=32 columns ----------------
// Hybrid sync = R9's flag-gated gather (one-shot issue) + R12's sentinel validity for
// data-before-signal ordering. Publishers do NOT drain before the flag store (flag =
// "issued"); consumers re-load only still-poisoned chunks (rare in-flight races).
// Poison schedule = R12 (proven race-free):
//   t ph1: hm_{t-1} gathered  ==> all WGs past ph2 of t-1 ==> poison rhbuf[(t-1)&1]
//   t ph2: rh_t gathered      ==> all WGs past ph1 of t   ==> poison hbuf[(t-1)&1]
__global__ __launch_bounds__(512) void k_scan(const _Float16* __restrict__ Ut,      // [3][n][k] f16
                                              const float* __restrict__ maskT,
                                              const _Float16* __restrict__ xprojT,
                                              unsigned long long* __restrict__ hbuf,   // [2][64][128] u64
                                              unsigned long long* __restrict__ rhbuf,  // [2][64][128] u64
                                              unsigned* __restrict__ fh, unsigned* __restrict__ fr,
                                              float* __restrict__ out) {
    __shared__ __align__(16) _Float16 Ulds[2 * JS * 512];   // 64KB: Uz,Ur [n][k] swizzled
    __shared__ __align__(16) _Float16 Stg[64 * 512];        // 64KB: exchange staging, swizzled
    char* StgB = (char*)Stg;
    int tid = threadIdx.x, l = tid & 63, w = tid >> 6;
    int lr = l & 15, lg = l >> 4;
    int mt = w >> 1, nt = w & 1;              // wave's (M,N) 16x16 tile
    int slot = blockIdx.x;
    int jsb = slot * JS;
    const int fidx = slot * 8 + w;            // this wave's flag index (x16 u32 = 64B stride)

    // ---- stage Uz, Ur into LDS (already transposed f16; add XOR swizzle) ----
    for (int c = tid; c < 2 * JS * 64; c += 512) {     // 16B chunks: 2 gates x 32 n x 64 chunks
        int g  = c >> 11;
        int n  = (c >> 6) & 31;
        int k16 = c & 63;
        uintx4 v = *(const uintx4*)(Ut + (size_t)g * 262144 + (size_t)(jsb + n) * 512 + k16 * 8);
        *(uintx4*)((char*)Ulds + g * 32768 + n * 1024 + ((k16 * 16) ^ ((n & 7) << 4))) = v;
    }
    // ---- preload U_h fragments into registers (static across t) ----
    half8 uhf[16];
    {
        const _Float16* UtH = Ut + (size_t)2 * 262144;
        int ncol = jsb + nt * 16 + lr;
#pragma unroll
        for (int j = 0; j < 16; j++)
            uhf[j] = *(const half8*)(UtH + (size_t)ncol * 512 + j * 32 + lg * 8);
    }
    __syncthreads();

    const char* UB = (const char*)Ulds + (nt * 16 + lr) * 1024;  // B-row base for Uz (Ur at +32KB)
    const int swz = (lr & 7) << 4;

    int row0 = mt * 16 + lg * 4;              // this thread's 4 C-rows (batch)
    int colg = jsb + nt * 16 + lr;            // this thread's C-col (global hidden index)

    float h4[4]  = {0.f, 0.f, 0.f, 0.f};
    float hm4[4] = {0.f, 0.f, 0.f, 0.f};

    const int punit = (mt * 16 + lg * 4 + (lr & 3)) * 128 + ((jsb + nt * 16) >> 2) + ((lr >> 2) & 3);
    const char* SB = StgB + (mt * 16 + lr) * 1024;    // A-frag row base in staging

    const _Float16* xzB = xprojT + (size_t)colg * 64 + row0;
    const _Float16* xrB = xzB + (size_t)16777216;
    const _Float16* xhB = xrB + (size_t)16777216;

    // ---------------- step 0: hm = 0, pure local ----------------
    {
        half4 xz0 = *(const half4*)(xzB);
        half4 xh0 = *(const half4*)(xhB);
        float4 m0 = *(const float4*)(maskT + row0);
#pragma unroll
        for (int i = 0; i < 4; i++) {
            float z  = __builtin_amdgcn_rcpf(1.f + __expf(-(float)xz0[i]));
            float hh = tanhf((float)xh0[i]);
            h4[i]  = (1.f - z) * hh;
            hm4[i] = ((float)m0[i]) * h4[i];
        }
        st_agent(hbuf + punit, pack_quad(hm4, lr));   // parity 0
        if (l == 0) st_flag(fh + fidx * 16, 1u);      // NO drain: flag = "issued"
    }

    for (int t = 1; t < T_; ++t) {
        const char* hmG = (const char*)(hbuf + ((t - 1) & 1) * 8192);
        unsigned long long* rhPsn = rhbuf + ((t - 1) & 1) * 8192;   // poison target, ph1
        unsigned long long* hPsn  = hbuf  + ((t - 1) & 1) * 8192;   // poison target, ph2
        unsigned long long* rhW   = rhbuf + (t & 1) * 8192;
        unsigned long long* hW    = hbuf  + (t & 1) * 8192;
        const char* rhG = (const char*)rhW;

        // issue this step's x loads early (drained by the gather WAITV)
        half4 xzp = *(const half4*)(xzB + (size_t)t * 32768);
        half4 xrp = *(const half4*)(xrB + (size_t)t * 32768);
        half4 xhp = *(const half4*)(xhB + (size_t)t * 32768);
        float4 mv = *(const float4*)(maskT + (size_t)t * 64 + row0);

        // ================= phase 1: flag-gated gather hm (sentinel retry), r then z =================
        __syncthreads();                 // all waves done reading Stg from prev phase
        poll_flags(fh, (unsigned)t, l);
        uintx4 gg[8];
        {
            unsigned vmask = 0;
#pragma unroll
            for (int it = 0; it < 8; ++it)
                gg[it] = ld16_agent(hmG + (w * 8 + it) * 1024 + l * 16);
            WAITV(0); SCB();
#pragma unroll
            for (int it = 0; it < 8; ++it) if (chunk_valid(gg[it])) vmask |= 1u << it;
            while (!__all(vmask == 255u)) {
#pragma unroll
                for (int it = 0; it < 8; ++it)
                    if (!(vmask & (1u << it)))
                        gg[it] = ld16_agent(hmG + (w * 8 + it) * 1024 + l * 16);
                WAITV(0); SCB();
#pragma unroll
                for (int it = 0; it < 8; ++it) if (chunk_valid(gg[it])) vmask |= 1u << it;
            }
        }
        st_agent(rhPsn + punit, ~0ull);   // poison rh[(t-1)&1]
        __syncthreads();
#pragma unroll
        for (int it = 0; it < 8; ++it)
            *(uintx4*)(StgB + (w * 8 + it) * 1024 + ((l * 16) ^ (it << 4))) = gg[it];
        __syncthreads();
        half8 af[16];
#pragma unroll
        for (int j = 0; j < 16; j++)
            af[j] = *(const half8*)(SB + ((j * 64 + lg * 16) ^ swz));
        // --- r first: its result gates the next rendezvous ---
        floatx4 accr = {0.f, 0.f, 0.f, 0.f};
#pragma unroll
        for (int j = 0; j < 16; j++) {
            int boff = (j * 64 + lg * 16) ^ swz;
            half8 br8 = *(const half8*)(UB + 32768 + boff);
            accr = __builtin_amdgcn_mfma_f32_16x16x32_f16(af[j], br8, accr, 0, 0, 0);
        }
        float rh4[4];
#pragma unroll
        for (int i = 0; i < 4; i++) {
            float rr = __builtin_amdgcn_rcpf(1.f + __expf(-((float)xrp[i] + accr[i])));
            rh4[i] = rr * hm4[i];
        }
        st_agent(rhW + punit, pack_quad(rh4, lr));
        if (l == 0) st_flag(fr + fidx * 16, (unsigned)t);   // NO drain
        // --- z while rh propagates to peers ---
        floatx4 accz = {0.f, 0.f, 0.f, 0.f};
#pragma unroll
        for (int j = 0; j < 16; j++) {
            int boff = (j * 64 + lg * 16) ^ swz;
            half8 bz8 = *(const half8*)(UB + boff);
            accz = __builtin_amdgcn_mfma_f32_16x16x32_f16(af[j], bz8, accz, 0, 0, 0);
        }
        float z4[4];
#pragma unroll
        for (int i = 0; i < 4; i++)
            z4[i] = __builtin_amdgcn_rcpf(1.f + __expf(-((float)xzp[i] + accz[i])));

        // ================= phase 2: flag-gated gather rh (sentinel retry), candidate + update =================
        __syncthreads();                 // all waves done reading Stg (af)
        poll_flags(fr, (unsigned)t, l);
        uintx4 gg2[8];
        {
            unsigned vmask = 0;
#pragma unroll
            for (int it = 0; it < 8; ++it)
                gg2[it] = ld16_agent(rhG + (w * 8 + it) * 1024 + l * 16);
            WAITV(0); SCB();
#pragma unroll
            for (int it = 0; it < 8; ++it) if (chunk_valid(gg2[it])) vmask |= 1u << it;
            while (!__all(vmask == 255u)) {
#pragma unroll
                for (int it = 0; it < 8; ++it)
                    if (!(vmask & (1u << it)))
                        gg2[it] = ld16_agent(rhG + (w * 8 + it) * 1024 + l * 16);
                WAITV(0); SCB();
#pragma unroll
                for (int it = 0; it < 8; ++it) if (chunk_valid(gg2[it])) vmask |= 1u << it;
            }
        }
        st_agent(hPsn + punit, ~0ull);   // poison h[(t-1)&1]
        __syncthreads();
#pragma unroll
        for (int it = 0; it < 8; ++it)
            *(uintx4*)(StgB + (w * 8 + it) * 1024 + ((l * 16) ^ (it << 4))) = gg2[it];
        __syncthreads();
        half8 af2[16];
#pragma unroll
        for (int j = 0; j < 16; j++)
            af2[j] = *(const half8*)(SB + ((j * 64 + lg * 16) ^ swz));
        floatx4 acch0 = {0.f, 0.f, 0.f, 0.f}, acch1 = {0.f, 0.f, 0.f, 0.f};
#pragma unroll
        for (int j = 0; j < 16; j += 2) {
            acch0 = __builtin_amdgcn_mfma_f32_16x16x32_f16(af2[j],     uhf[j],     acch0, 0, 0, 0);
            acch1 = __builtin_amdgcn_mfma_f32_16x16x32_f16(af2[j + 1], uhf[j + 1], acch1, 0, 0, 0);
        }
#pragma unroll
        for (int i = 0; i < 4; i++) {
            float hh = tanhf((float)xhp[i] + acch0[i] + acch1[i]);
            h4[i]  = z4[i] * hm4[i] + (1.f - z4[i]) * hh;
            hm4[i] = ((float)mv[i]) * h4[i];
        }
        st_agent(hW + punit, pack_quad(hm4, lr));
        if (l == 0) st_flag(fh + fidx * 16, (unsigned)(t + 1));   // NO drain
    }

#pragma unroll
    for (int i = 0; i < 4; i++)
        out[(size_t)(row0 + i) * 512 + colg] = h4[i];
}

extern "C" void kernel_launch(void* const* d_in, const int* in_sizes, int n_in,
                              void* d_out, int out_size, void* d_ws, size_t ws_size,
                              hipStream_t stream) {
    (void)in_sizes; (void)n_in; (void)out_size; (void)ws_size;
    const float* X  = (const float*)d_in[0];
    const float* Wz = (const float*)d_in[1];
    const float* Uz = (const float*)d_in[2];
    const float* bz = (const float*)d_in[3];
    const float* Wr = (const float*)d_in[4];
    const float* Ur = (const float*)d_in[5];
    const float* br = (const float*)d_in[6];
    const float* Wh = (const float*)d_in[7];
    const float* Uh = (const float*)d_in[8];
    const float* bh = (const float*)d_in[9];
    const int* mask = (const int*)d_in[10];
    float* out = (float*)d_out;

    char* ws = (char*)d_ws;
    unsigned* fh = (unsigned*)ws;                                    // 8KB: 128 per-wave flags, 64B stride
    unsigned* fr = (unsigned*)(ws + 8192);                           // 8KB
    unsigned long long* hbuf  = (unsigned long long*)(ws + 16384);              // 128KB [2][64][128]
    unsigned long long* rhbuf = (unsigned long long*)(ws + 16384 + 131072);     // 128KB
    _Float16* Xh     = (_Float16*)(ws + 16384 + 2 * 131072);                    // 32MB
    _Float16* Wt     = (_Float16*)(ws + 16384 + 2 * 131072 + 33554432);         // 1.5MB
    _Float16* Ut     = (_Float16*)(ws + 16384 + 2 * 131072 + 33554432 + 1572864);           // 1.5MB
    _Float16* xprojT = (_Float16*)(ws + 16384 + 2 * 131072 + 33554432 + 2 * 1572864);       // 96MB
    float*    maskT  = (float*)(ws + 16384 + 2 * 131072 + 33554432 + 2 * 1572864 + 100663296); // 128KB

    hipMemsetAsync(ws, 0, 16384, stream);                    // flags = 0
    hipMemsetAsync(ws + 16384, 0xFF, 2 * 131072, stream);    // exchange buffers = poison
    hipLaunchKernelGGL(k_cvtX, dim3(8192), dim3(256), 0, stream, X, Xh);
    hipLaunchKernelGGL(k_cvtW, dim3(8, 8, 3), dim3(256), 0, stream, Wz, Wr, Wh, Wt);
    hipLaunchKernelGGL(k_cvtW, dim3(8, 8, 3), dim3(256), 0, stream, Uz, Ur, Uh, Ut);
    hipLaunchKernelGGL(k_cvtM, dim3(128), dim3(256), 0, stream, mask, maskT);
    hipLaunchKernelGGL(k_gemm, dim3(256, 4, 3), dim3(256), 0, stream, Xh, Wt, bz, br, bh, xprojT);
    hipLaunchKernelGGL(k_scan, dim3(NWG), dim3(512), 0, stream, Ut, maskT, xprojT,
                       hbuf, rhbuf, fh, fr, out);
}

// Round 14
// 3769.318 us; speedup vs baseline: 3.8654x; 1.0471x over previous
//
#include <hip/hip_runtime.h>
#include <hip/hip_fp16.h>

#define B_   64
#define T_   512
#define DINc 512
#define D_   512
#define NWG  16
#define JS   32   // output columns per workgroup in scan

typedef _Float16 half8 __attribute__((ext_vector_type(8)));
typedef _Float16 half4 __attribute__((ext_vector_type(4)));
typedef float   floatx4 __attribute__((ext_vector_type(4)));
typedef unsigned uintx4 __attribute__((ext_vector_type(4)));

#define WAITV(N) asm volatile("s_waitcnt vmcnt(" #N ")" ::: "memory")
#define SCB()    __builtin_amdgcn_sched_barrier(0)

// ---------------- X convert + transpose: Xh[m][k] = (f16) X[b][t][k], m = t*64+b ----------------
__global__ __launch_bounds__(256) void k_cvtX(const float* __restrict__ X, _Float16* __restrict__ Xh) {
    int idx = blockIdx.x * 256 + threadIdx.x;
    int m  = idx >> 6;
    int k8 = idx & 63;
    int b = m & 63, t = m >> 6;
    const float* src = X + ((size_t)(b * T_ + t)) * DINc + k8 * 8;
    float4 f0 = *(const float4*)(src);
    float4 f1 = *(const float4*)(src + 4);
    half8 h;
    h[0] = (_Float16)f0.x; h[1] = (_Float16)f0.y; h[2] = (_Float16)f0.z; h[3] = (_Float16)f0.w;
    h[4] = (_Float16)f1.x; h[5] = (_Float16)f1.y; h[6] = (_Float16)f1.z; h[7] = (_Float16)f1.w;
    *(half8*)(Xh + (size_t)m * DINc + k8 * 8) = h;
}

// ---------------- generic 3-matrix transpose + convert: Mt[g][n][k] = (f16) M_g[k][n] ----------------
__global__ __launch_bounds__(256) void k_cvtW(const float* __restrict__ M0, const float* __restrict__ M1,
                                              const float* __restrict__ M2, _Float16* __restrict__ Mt) {
    __shared__ float tile[64][65];
    int g = blockIdx.z;
    const float* W = (g == 0) ? M0 : ((g == 1) ? M1 : M2);
    int n0 = blockIdx.x * 64, k0 = blockIdx.y * 64;
    int c = threadIdx.x & 63, r4 = threadIdx.x >> 6;
#pragma unroll
    for (int i = 0; i < 16; ++i) {
        int k = r4 + i * 4;
        tile[k][c] = W[(size_t)(k0 + k) * D_ + n0 + c];
    }
    __syncthreads();
    _Float16* out = Mt + (size_t)g * D_ * DINc;
#pragma unroll
    for (int i = 0; i < 16; ++i) {
        int n = r4 + i * 4;
        out[(size_t)(n0 + n) * DINc + k0 + c] = (_Float16)tile[c][n];
    }
}

// ---------------- mask transpose: maskT[t][b] = (float) mask[b][t] ----------------
__global__ __launch_bounds__(256) void k_cvtM(const int* __restrict__ mask, float* __restrict__ maskT) {
    int idx = blockIdx.x * 256 + threadIdx.x;   // 32768
    int t = idx >> 6, b = idx & 63;
    maskT[idx] = (float)mask[(size_t)b * T_ + t];
}

// ---- input projections: xprojT[g][t][n][b] = (Xh[m] @ W_g)[n] + b_g[n], m=t*64+b (f16) ----
__global__ __launch_bounds__(256) void k_gemm(const _Float16* __restrict__ Xh, const _Float16* __restrict__ Wt,
                                              const float* __restrict__ bz, const float* __restrict__ br,
                                              const float* __restrict__ bh, _Float16* __restrict__ xprojT) {
    __shared__ _Float16 As[128 * 32];
    __shared__ _Float16 Bs[128 * 32];
    int g = blockIdx.z;
    const _Float16* Wg = Wt + (size_t)g * 512 * 512;
    const float* bias = (g == 0) ? bz : ((g == 1) ? br : bh);
    _Float16* out = xprojT + (size_t)g * 16777216;
    int mb = blockIdx.x * 128, nb = blockIdx.y * 128;
    int tid = threadIdx.x, l = tid & 63, w = tid >> 6;
    int wr = w >> 1, wc = w & 1;
    int lr = l & 15, lg = l >> 4;

    floatx4 acc[4][4] = {};

    int ga0 = tid, ga1 = tid + 256;
    int ra0 = ga0 >> 2, ca0 = (ga0 & 3) * 8;
    int ra1 = ga1 >> 2, ca1 = (ga1 & 3) * 8;

    uint4 pa0, pa1, pb0, pb1;
    pa0 = *(const uint4*)(Xh + (size_t)(mb + ra0) * 512 + ca0);
    pa1 = *(const uint4*)(Xh + (size_t)(mb + ra1) * 512 + ca1);
    pb0 = *(const uint4*)(Wg + (size_t)(nb + ra0) * 512 + ca0);
    pb1 = *(const uint4*)(Wg + (size_t)(nb + ra1) * 512 + ca1);

    for (int kt = 0; kt < 16; ++kt) {
        __syncthreads();
        *(uint4*)(&As[ga0 * 8]) = pa0;
        *(uint4*)(&As[ga1 * 8]) = pa1;
        *(uint4*)(&Bs[ga0 * 8]) = pb0;
        *(uint4*)(&Bs[ga1 * 8]) = pb1;
        __syncthreads();
        if (kt < 15) {
            int kb = (kt + 1) * 32;
            pa0 = *(const uint4*)(Xh + (size_t)(mb + ra0) * 512 + kb + ca0);
            pa1 = *(const uint4*)(Xh + (size_t)(mb + ra1) * 512 + kb + ca1);
            pb0 = *(const uint4*)(Wg + (size_t)(nb + ra0) * 512 + kb + ca0);
            pb1 = *(const uint4*)(Wg + (size_t)(nb + ra1) * 512 + kb + ca1);
        }
        half8 af[4], bf[4];
#pragma unroll
        for (int mi = 0; mi < 4; mi++) af[mi] = *(const half8*)(&As[(wr * 64 + mi * 16 + lr) * 32 + lg * 8]);
#pragma unroll
        for (int ni = 0; ni < 4; ni++) bf[ni] = *(const half8*)(&Bs[(wc * 64 + ni * 16 + lr) * 32 + lg * 8]);
#pragma unroll
        for (int mi = 0; mi < 4; mi++)
#pragma unroll
            for (int ni = 0; ni < 4; ni++)
                acc[mi][ni] = __builtin_amdgcn_mfma_f32_16x16x32_f16(af[mi], bf[ni], acc[mi][ni], 0, 0, 0);
    }

#pragma unroll
    for (int ni = 0; ni < 4; ni++) {
        int col = nb + wc * 64 + ni * 16 + lr;
        float bv = bias[col];
#pragma unroll
        for (int mi = 0; mi < 4; mi++) {
            int row = mb + wr * 64 + mi * 16 + lg * 4;
            int tt = row >> 6, bb = row & 63;
            half4 hv;
#pragma unroll
            for (int i = 0; i < 4; i++) hv[i] = (_Float16)(acc[mi][ni][i] + bv);
            *(half4*)(out + (size_t)tt * 32768 + (size_t)col * 64 + bb) = hv;
        }
    }
}

// -------- agent-scope (device-coherent) primitives — PROVEN path (R2/R6/R9) --------
__device__ __forceinline__ void st_agent(unsigned long long* p, unsigned long long v) {
    __hip_atomic_store(p, v, __ATOMIC_RELAXED, __HIP_MEMORY_SCOPE_AGENT);
}
__device__ __forceinline__ unsigned ld_flag(const unsigned* p) {
    return __hip_atomic_load(p, __ATOMIC_RELAXED, __HIP_MEMORY_SCOPE_AGENT);
}
__device__ __forceinline__ void st_flag(unsigned* p, unsigned v) {
    __hip_atomic_store(p, v, __ATOMIC_RELAXED, __HIP_MEMORY_SCOPE_AGENT);
}
__device__ __forceinline__ uintx4 ld16_agent(const void* p) {
    uintx4 r;
    asm volatile("global_load_dwordx4 %0, %1, off sc0 sc1" : "=v"(r) : "v"(p) : "memory");
    return r;
}

// pack 4 fp32 (4 rows, 1 col) -> 8B row-major unit (1 row, 4 cols), 2-round butterfly (R6-proven)
__device__ __forceinline__ unsigned long long pack_quad(const float v4[4], int lr) {
    unsigned long long unit = 0;
    int j = lr & 3;
#pragma unroll
    for (int i = 0; i < 4; i++) {
        _Float16 hv = (_Float16)v4[i];
        unsigned int v = (unsigned int)__builtin_bit_cast(unsigned short, hv);
        unsigned int o1 = __shfl_xor(v, 1, 64);
        unsigned int pair = (lr & 1) ? (o1 | (v << 16)) : (v | (o1 << 16));
        unsigned int q2 = __shfl_xor(pair, 2, 64);
        unsigned long long u = (lr & 2) ? ((unsigned long long)q2 | ((unsigned long long)pair << 32))
                                        : ((unsigned long long)pair | ((unsigned long long)q2 << 32));
        if (i == j) unit = u;
    }
    return unit;
}

// every-wave poll of 128 per-wave flags (lanes 0..63 -> flags 0..63, +64 -> 64..127)
__device__ __forceinline__ void poll_flags(const unsigned* f, unsigned need, int l) {
    for (;;) {
        unsigned v0 = ld_flag(f + l * 16);
        unsigned v1 = ld_flag(f + (64 + l) * 16);
        if (__all(v0 >= need && v1 >= need)) break;
    }
    SCB();
}

// ---------------- recurrent scan: 16 WGs x 512 threads, each owns JS=32 columns ----------------
// Sync skeleton = R6 (agent-relaxed data + monotonic epoch flags), with per-WAVE flags
// (publish-early, no publisher syncthreads) and every-wave independent polling.  [R9 optimum]
__global__ __launch_bounds__(512) void k_scan(const _Float16* __restrict__ Ut,      // [3][n][k] f16
                                              const float* __restrict__ maskT,
                                              const _Float16* __restrict__ xprojT,
                                              unsigned long long* __restrict__ hbuf,   // [2][64][128] u64
                                              unsigned long long* __restrict__ rhbuf,  // [2][64][128] u64
                                              unsigned* __restrict__ fh, unsigned* __restrict__ fr,
                                              float* __restrict__ out) {
    __shared__ __align__(16) _Float16 Ulds[2 * JS * 512];   // 64KB: Uz,Ur [n][k] swizzled
    __shared__ __align__(16) _Float16 Stg[64 * 512];        // 64KB: exchange staging, swizzled
    char* StgB = (char*)Stg;
    int tid = threadIdx.x, l = tid & 63, w = tid >> 6;
    int lr = l & 15, lg = l >> 4;
    int mt = w >> 1, nt = w & 1;              // wave's (M,N) 16x16 tile
    int slot = blockIdx.x;
    int jsb = slot * JS;
    const int fidx = slot * 8 + w;            // this wave's flag index (x16 u32 = 64B stride)

    // ---- stage Uz, Ur into LDS (already transposed f16; add XOR swizzle) ----
    for (int c = tid; c < 2 * JS * 64; c += 512) {     // 16B chunks: 2 gates x 32 n x 64 chunks
        int g  = c >> 11;
        int n  = (c >> 6) & 31;
        int k16 = c & 63;
        uintx4 v = *(const uintx4*)(Ut + (size_t)g * 262144 + (size_t)(jsb + n) * 512 + k16 * 8);
        *(uintx4*)((char*)Ulds + g * 32768 + n * 1024 + ((k16 * 16) ^ ((n & 7) << 4))) = v;
    }
    // ---- preload U_h fragments into registers (static across t) ----
    half8 uhf[16];
    {
        const _Float16* UtH = Ut + (size_t)2 * 262144;
        int ncol = jsb + nt * 16 + lr;
#pragma unroll
        for (int j = 0; j < 16; j++)
            uhf[j] = *(const half8*)(UtH + (size_t)ncol * 512 + j * 32 + lg * 8);
    }
    __syncthreads();

    const char* UB = (const char*)Ulds + (nt * 16 + lr) * 1024;  // B-row base for Uz (Ur at +32KB)
    const int swz = (lr & 7) << 4;

    int row0 = mt * 16 + lg * 4;              // this thread's 4 C-rows (batch)
    int colg = jsb + nt * 16 + lr;            // this thread's C-col (global hidden index)

    float h4[4]  = {0.f, 0.f, 0.f, 0.f};
    float hm4[4] = {0.f, 0.f, 0.f, 0.f};

    const int punit = (mt * 16 + lg * 4 + (lr & 3)) * 128 + ((jsb + nt * 16) >> 2) + ((lr >> 2) & 3);
    const char* SB = StgB + (mt * 16 + lr) * 1024;    // A-frag row base in staging

    const _Float16* xzB = xprojT + (size_t)colg * 64 + row0;
    const _Float16* xrB = xzB + (size_t)16777216;
    const _Float16* xhB = xrB + (size_t)16777216;

    // ---------------- step 0: hm = 0, pure local ----------------
    {
        half4 xz0 = *(const half4*)(xzB);
        half4 xh0 = *(const half4*)(xhB);
        float4 m0 = *(const float4*)(maskT + row0);
#pragma unroll
        for (int i = 0; i < 4; i++) {
            float z  = __builtin_amdgcn_rcpf(1.f + __expf(-(float)xz0[i]));
            float hh = tanhf((float)xh0[i]);
            h4[i]  = (1.f - z) * hh;
            hm4[i] = ((float)m0[i]) * h4[i];
        }
        st_agent(hbuf + punit, pack_quad(hm4, lr));   // parity 0
        WAITV(0);
        if (l == 0) st_flag(fh + fidx * 16, 1u);      // per-wave flag, publish-early
    }

    for (int t = 1; t < T_; ++t) {
        const char* hmG = (const char*)(hbuf + ((t - 1) & 1) * 8192);
        unsigned long long* rhW = rhbuf + (t & 1) * 8192;
        unsigned long long* hW  = hbuf  + (t & 1) * 8192;
        const char* rhG = (const char*)rhW;

        // issue this step's x loads early (counted by the staging vmcnt waits)
        half4 xzp = *(const half4*)(xzB + (size_t)t * 32768);
        half4 xrp = *(const half4*)(xrB + (size_t)t * 32768);
        half4 xhp = *(const half4*)(xhB + (size_t)t * 32768);
        float4 mv = *(const float4*)(maskT + (size_t)t * 64 + row0);

        // ================= phase 1: r (then z off-path) =================
        __syncthreads();                 // all waves done reading Stg from prev phase
        poll_flags(fh, (unsigned)t, l);  // every wave polls independently
        {
            uintx4 gg[8];
#pragma unroll
            for (int it = 0; it < 8; ++it)
                gg[it] = ld16_agent(hmG + (w * 8 + it) * 1024 + l * 16);
            WAITV(4); SCB();
#pragma unroll
            for (int it = 0; it < 4; ++it)
                *(uintx4*)(StgB + (w * 8 + it) * 1024 + ((l * 16) ^ (it << 4))) = gg[it];
            WAITV(0); SCB();
#pragma unroll
            for (int it = 4; it < 8; ++it)
                *(uintx4*)(StgB + (w * 8 + it) * 1024 + ((l * 16) ^ (it << 4))) = gg[it];
        }
        __syncthreads();
        half8 af[16];
#pragma unroll
        for (int j = 0; j < 16; j++)
            af[j] = *(const half8*)(SB + ((j * 64 + lg * 16) ^ swz));
        // --- r first: its result gates the next rendezvous ---
        floatx4 accr = {0.f, 0.f, 0.f, 0.f};
#pragma unroll
        for (int j = 0; j < 16; j++) {
            int boff = (j * 64 + lg * 16) ^ swz;
            half8 br8 = *(const half8*)(UB + 32768 + boff);
            accr = __builtin_amdgcn_mfma_f32_16x16x32_f16(af[j], br8, accr, 0, 0, 0);
        }
        float rh4[4];
#pragma unroll
        for (int i = 0; i < 4; i++) {
            float rr = __builtin_amdgcn_rcpf(1.f + __expf(-((float)xrp[i] + accr[i])));
            rh4[i] = rr * hm4[i];
        }
        st_agent(rhW + punit, pack_quad(rh4, lr));
        WAITV(0);
        if (l == 0) st_flag(fr + fidx * 16, (unsigned)t);
        // --- z while rh propagates to peers ---
        floatx4 accz = {0.f, 0.f, 0.f, 0.f};
#pragma unroll
        for (int j = 0; j < 16; j++) {
            int boff = (j * 64 + lg * 16) ^ swz;
            half8 bz8 = *(const half8*)(UB + boff);
            accz = __builtin_amdgcn_mfma_f32_16x16x32_f16(af[j], bz8, accz, 0, 0, 0);
        }
        float z4[4];
#pragma unroll
        for (int i = 0; i < 4; i++)
            z4[i] = __builtin_amdgcn_rcpf(1.f + __expf(-((float)xzp[i] + accz[i])));

        // ================= phase 2: candidate + update =================
        __syncthreads();                 // all waves done reading Stg (af)
        poll_flags(fr, (unsigned)t, l);
        {
            uintx4 gg[8];
#pragma unroll
            for (int it = 0; it < 8; ++it)
                gg[it] = ld16_agent(rhG + (w * 8 + it) * 1024 + l * 16);
            WAITV(4); SCB();
#pragma unroll
            for (int it = 0; it < 4; ++it)
                *(uintx4*)(StgB + (w * 8 + it) * 1024 + ((l * 16) ^ (it << 4))) = gg[it];
            WAITV(0); SCB();
#pragma unroll
            for (int it = 4; it < 8; ++it)
                *(uintx4*)(StgB + (w * 8 + it) * 1024 + ((l * 16) ^ (it << 4))) = gg[it];
        }
        __syncthreads();
        half8 af2[16];
#pragma unroll
        for (int j = 0; j < 16; j++)
            af2[j] = *(const half8*)(SB + ((j * 64 + lg * 16) ^ swz));
        floatx4 acch0 = {0.f, 0.f, 0.f, 0.f}, acch1 = {0.f, 0.f, 0.f, 0.f};
#pragma unroll
        for (int j = 0; j < 16; j += 2) {
            acch0 = __builtin_amdgcn_mfma_f32_16x16x32_f16(af2[j],     uhf[j],     acch0, 0, 0, 0);
            acch1 = __builtin_amdgcn_mfma_f32_16x16x32_f16(af2[j + 1], uhf[j + 1], acch1, 0, 0, 0);
        }
#pragma unroll
        for (int i = 0; i < 4; i++) {
            float hh = tanhf((float)xhp[i] + acch0[i] + acch1[i]);
            h4[i]  = z4[i] * hm4[i] + (1.f - z4[i]) * hh;
            hm4[i] = ((float)mv[i]) * h4[i];
        }
        st_agent(hW + punit, pack_quad(hm4, lr));
        WAITV(0);
        if (l == 0) st_flag(fh + fidx * 16, (unsigned)(t + 1));
    }

#pragma unroll
    for (int i = 0; i < 4; i++)
        out[(size_t)(row0 + i) * 512 + colg] = h4[i];
}

extern "C" void kernel_launch(void* const* d_in, const int* in_sizes, int n_in,
                              void* d_out, int out_size, void* d_ws, size_t ws_size,
                              hipStream_t stream) {
    (void)in_sizes; (void)n_in; (void)out_size; (void)ws_size;
    const float* X  = (const float*)d_in[0];
    const float* Wz = (const float*)d_in[1];
    const float* Uz = (const float*)d_in[2];
    const float* bz = (const float*)d_in[3];
    const float* Wr = (const float*)d_in[4];
    const float* Ur = (const float*)d_in[5];
    const float* br = (const float*)d_in[6];
    const float* Wh = (const float*)d_in[7];
    const float* Uh = (const float*)d_in[8];
    const float* bh = (const float*)d_in[9];
    const int* mask = (const int*)d_in[10];
    float* out = (float*)d_out;

    char* ws = (char*)d_ws;
    unsigned* fh = (unsigned*)ws;                                    // 8KB: 128 per-wave flags, 64B stride
    unsigned* fr = (unsigned*)(ws + 8192);                           // 8KB
    unsigned long long* hbuf  = (unsigned long long*)(ws + 16384);              // 128KB [2][64][128]
    unsigned long long* rhbuf = (unsigned long long*)(ws + 16384 + 131072);     // 128KB
    _Float16* Xh     = (_Float16*)(ws + 16384 + 2 * 131072);                    // 32MB
    _Float16* Wt     = (_Float16*)(ws + 16384 + 2 * 131072 + 33554432);         // 1.5MB
    _Float16* Ut     = (_Float16*)(ws + 16384 + 2 * 131072 + 33554432 + 1572864);           // 1.5MB
    _Float16* xprojT = (_Float16*)(ws + 16384 + 2 * 131072 + 33554432 + 2 * 1572864);       // 96MB
    float*    maskT  = (float*)(ws + 16384 + 2 * 131072 + 33554432 + 2 * 1572864 + 100663296); // 128KB

    hipMemsetAsync(ws, 0, 16384, stream);
    hipLaunchKernelGGL(k_cvtX, dim3(8192), dim3(256), 0, stream, X, Xh);
    hipLaunchKernelGGL(k_cvtW, dim3(8, 8, 3), dim3(256), 0, stream, Wz, Wr, Wh, Wt);
    hipLaunchKernelGGL(k_cvtW, dim3(8, 8, 3), dim3(256), 0, stream, Uz, Ur, Uh, Ut);
    hipLaunchKernelGGL(k_cvtM, dim3(128), dim3(256), 0, stream, mask, maskT);
    hipLaunchKernelGGL(k_gemm, dim3(256, 4, 3), dim3(256), 0, stream, Xh, Wt, bz, br, bh, xprojT);
    hipLaunchKernelGGL(k_scan, dim3(NWG), dim3(512), 0, stream, Ut, maskT, xprojT,
                       hbuf, rhbuf, fh, fr, out);
}